// Round 12
// baseline (62.234 us; speedup 1.0000x reference)
//
#include <hip/hip_runtime.h>
#include <hip/hip_bf16.h>

#define LEN   2048
#define KNB   32
#define HID   128
#define FS    512   // fp8 bytes/feature-row: 32 16B-blocks, XOR-swizzle closed

typedef unsigned long long ull;
typedef unsigned int uint32;
typedef float f32x4 __attribute__((ext_vector_type(4)));
typedef __bf16 bf16x8v __attribute__((ext_vector_type(8)));

// LDS-only barrier: output stores (vmcnt) stay in flight across rows.
__device__ __forceinline__ void bar_lgkm() {
    asm volatile("s_waitcnt lgkmcnt(0)" ::: "memory");
    __builtin_amdgcn_s_barrier();
    asm volatile("" ::: "memory");
}

// ---------------------------------------------------------------------------
// Kernel 0: prep — pack CA+mask as float4; convert W_edge f32 -> fp8 e4m3.
// ---------------------------------------------------------------------------
__global__ __launch_bounds__(256) void prep_kernel(
    const float* __restrict__ X, const float* __restrict__ mask,
    const float* __restrict__ W_edge,
    float4* __restrict__ CAm, int* __restrict__ Wf8) {
    const int t = blockIdx.x * 256 + threadIdx.x;
    if (t < 2 * LEN) {
        const float* p = X + (size_t)t * 12;
        CAm[t] = make_float4(p[3], p[4], p[5],
                             __fmul_rn(__fsub_rn(1.0f, mask[t]), 1000000.0f));
    }
    if (t < 13312) {
        const float4 w = ((const float4*)W_edge)[t];
        int r = __builtin_amdgcn_cvt_pk_fp8_f32(w.x, w.y, 0, false);
        r = __builtin_amdgcn_cvt_pk_fp8_f32(w.z, w.w, r, true);
        Wf8[t] = r;
    }
}

// ---------------------------------------------------------------------------
// Kernel 1: exact top-K=32 via histogram-select (proven ~10us standalone).
// ---------------------------------------------------------------------------
__global__ __launch_bounds__(256) void topk_kernel(
    const float4* __restrict__ CAm, float* __restrict__ eidx_out) {
    const int row = blockIdx.x;
    const int b = row >> 11;
    const int i = row & (LEN - 1);
    const int tid = threadIdx.x;

    __shared__ int hist[512];
    __shared__ ull cand[LEN];
    __shared__ int candcnt;
    __shared__ int selB;

    const float4* C = CAm + (size_t)b * LEN;
    const float4 ci = C[i];

    uint32 d2b[8];
#pragma unroll
    for (int q = 0; q < 8; ++q) {
        const float4 cj = C[q * 256 + tid];
        float dx = __fsub_rn(ci.x, cj.x);
        float dy = __fsub_rn(ci.y, cj.y);
        float dz = __fsub_rn(ci.z, cj.z);
        float d2 = __fadd_rn(__fadd_rn(__fmul_rn(dx, dx), __fmul_rn(dy, dy)),
                             __fmul_rn(dz, dz));
        d2 = __fadd_rn(d2, cj.w);
        d2b[q] = __float_as_uint(d2);
    }

    hist[tid] = 0; hist[tid + 256] = 0;
    if (tid == 0) candcnt = 0;
    __syncthreads();
#pragma unroll
    for (int q = 0; q < 8; ++q) atomicAdd(&hist[d2b[q] >> 22], 1);
    __syncthreads();

    if (tid < 64) {
        int loc[8];
        int s = 0;
#pragma unroll
        for (int t = 0; t < 8; ++t) { loc[t] = hist[tid * 8 + t]; s += loc[t]; }
        int incl = s;
#pragma unroll
        for (int off = 1; off < 64; off <<= 1) {
            int o = __shfl_up(incl, off, 64);
            if (tid >= off) incl += o;
        }
        const int excl = incl - s;
        if (excl < KNB && incl >= KNB) {
            int c = excl;
#pragma unroll
            for (int t = 0; t < 8; ++t) {
                int c2 = c + loc[t];
                if (c < KNB && c2 >= KNB) selB = tid * 8 + t;
                c = c2;
            }
        }
    }
    __syncthreads();
    const uint32 B = (uint32)selB;

#pragma unroll
    for (int q = 0; q < 8; ++q) {
        if ((d2b[q] >> 22) <= B) {
            int p = atomicAdd(&candcnt, 1);
            cand[p] = (((ull)d2b[q]) << 32) | (uint32)(q * 256 + tid);
        }
    }
    __syncthreads();
    const int M = candcnt;

    for (int c = tid; c < M; c += 256) {
        const ull k = cand[c];
        int r = 0;
        for (int m = 0; m < M; ++m) r += (cand[m] < k);
        if (r < KNB)
            eidx_out[(size_t)row * KNB + r] = (float)(uint32)(k & 0xFFFFFFFFull);
    }
}

// ---------------------------------------------------------------------------
// Kernel 2: 8 rows/block, 512 thr, 512 blocks (2 blocks/CU, single pass).
// 2 rows per barrier pair: [GEMM rowA+rowB + bf16 scatter] bar
// [LN A + LN B + features(next 2 rows)] bar. fp8 W register-resident.
// LDS ~70.2 KB: 2x featF8, 2x bf16 hbuf, 8-row gather state.
// ---------------------------------------------------------------------------
__device__ __forceinline__ void load_res_atoms(const float* __restrict__ p, float* dst) {
    const float Nx = p[0], Ny = p[1], Nz = p[2];
    const float Ax = p[3], Ay = p[4], Az = p[5];
    const float Cx = p[6], Cy = p[7], Cz = p[8];
    const float Ox = p[9], Oy = p[10], Oz = p[11];
    const float bx = Ax - Nx, by = Ay - Ny, bz = Az - Nz;
    const float cx = Cx - Ax, cy = Cy - Ay, cz = Cz - Az;
    const float axv = by * cz - bz * cy;
    const float ayv = bz * cx - bx * cz;
    const float azv = bx * cy - by * cx;
    dst[0] = Nx;  dst[1] = Ny;  dst[2] = Nz;
    dst[3] = Ax;  dst[4] = Ay;  dst[5] = Az;
    dst[6] = Cx;  dst[7] = Cy;  dst[8] = Cz;
    dst[9] = Ox;  dst[10] = Oy; dst[11] = Oz;
    dst[12] = -0.58273431f * axv + 0.56802827f * bx + -0.54067466f * cx + Ax;
    dst[13] = -0.58273431f * ayv + 0.56802827f * by + -0.54067466f * cy + Ay;
    dst[14] = -0.58273431f * azv + 0.56802827f * bz + -0.54067466f * cz + Az;
}

__device__ __forceinline__ int pk4(float a, float b, float c, float d) {
    int r = __builtin_amdgcn_cvt_pk_fp8_f32(a, b, 0, false);
    return __builtin_amdgcn_cvt_pk_fp8_f32(c, d, r, true);
}

// chain constants exp(-1.1377778 * (2j+1)), j = 0..3
#define E1  3.2053337e-1f
#define E3  3.2931300e-2f
#define E5  3.3834001e-3f
#define E7  3.4760500e-4f

__device__ __forceinline__ void compute_features(
    int tid, int Ri, int Ci,
    const float* __restrict__ wposL,
    const int* jR, const int* jC,
    const float (*natoms)[15], const float* iatoms,
    unsigned char* featF8) {
    {
        const int e = tid >> 4, p = tid & 15;
        const int drel = jR[e] - Ri;
        const int same = (jC[e] == Ci);
        int dc = drel + 32;
        dc = dc < 0 ? 0 : (dc > 64 ? 64 : dc);
        const int df = same ? dc : 65;
        const float v = wposL[p * 66 + df];
        const int pb = __builtin_amdgcn_cvt_pk_fp8_f32(v, 0.0f, 0, false);
        featF8[e * FS + ((e & 7) << 4) + p] = (unsigned char)(pb & 0xFF);
    }
#pragma unroll
    for (int it = 0; it < 2; ++it) {
        const int task = tid + it * 512;
        if (task < 800) {
            const int mn = task >> 5, e = task & 31;
            const int m = mn / 5, n = mn - m * 5;
            const float ax = iatoms[m * 3 + 0];
            const float ay = iatoms[m * 3 + 1];
            const float az = iatoms[m * 3 + 2];
            const float* na = &natoms[e][n * 3];
            const float dx = ax - na[0], dy = ay - na[1], dz = az - na[2];
            const float D = sqrtf(dx * dx + dy * dy + dz * dz + 1e-6f);
            const float Dc = fminf(D, 40.0f);
            const float v4 = Dc - 7.3333333f;
            const float A4  = __expf(-0.64f * v4 * v4);
            const float C4  = __expf(1.7066667f * v4);
            const float Ci4 = 1.0f / C4;
            int4 w4;
            {
                const float f3 = A4 * Ci4 * E1;
                const float f2 = f3 * Ci4 * E3;
                const float f1 = f2 * Ci4 * E5;
                const float f0 = f1 * Ci4 * E7;
                w4.x = pk4(f0, f1, f2, f3);
            }
            {
                const float f5 = A4 * C4 * E1;
                const float f6 = f5 * C4 * E3;
                const float f7 = f6 * C4 * E5;
                w4.y = pk4(A4, f5, f6, f7);
            }
            const float v12 = Dc - 18.0f;
            const float A12  = __expf(-0.64f * v12 * v12);
            const float C12  = C4 * 1.24140e-8f;
            const float Ci12 = Ci4 * 8.05543e7f;
            {
                const float f11 = A12 * Ci12 * E1;
                const float f10 = f11 * Ci12 * E3;
                const float f9  = f10 * Ci12 * E5;
                const float f8  = f9  * Ci12 * E7;
                w4.z = pk4(f8, f9, f10, f11);
            }
            {
                const float f13 = A12 * C12 * E1;
                const float f14 = f13 * C12 * E3;
                const float f15 = f14 * C12 * E5;
                w4.w = pk4(A12, f13, f14, f15);
            }
            *(int4*)(featF8 + e * FS + (((1 + mn) ^ (e & 7)) << 4)) = w4;
        }
    }
}

__device__ __forceinline__ void gemm_row(
    const unsigned char* feat, const long* wreg, int lr, int lg,
    f32x4& acc0, f32x4& acc1) {
    const int sw = lr & 7;
    const int mb = lg >> 1;
    const unsigned char* fb0 = feat + lr * FS + (lg & 1) * 8;
    const unsigned char* fb1 = feat + (16 + lr) * FS + (lg & 1) * 8;
#pragma unroll
    for (int ks = 0; ks < 13; ++ks) {
        const int moff = ((2 * ks + mb) ^ sw) << 4;
        const long a0 = *(const long*)(fb0 + moff);
        const long a1 = *(const long*)(fb1 + moff);
        acc0 = __builtin_amdgcn_mfma_f32_16x16x32_fp8_fp8(a0, wreg[ks], acc0, 0, 0, 0);
        acc1 = __builtin_amdgcn_mfma_f32_16x16x32_fp8_fp8(a1, wreg[ks], acc1, 0, 0, 0);
    }
}

__device__ __forceinline__ void ln_store(
    const __bf16* hb, int row, int tid,
    const float* __restrict__ lng, const float* __restrict__ lnb,
    float* __restrict__ outE) {
    const int g = tid >> 4, l2 = tid & 15;
    const bf16x8v hv = *(const bf16x8v*)(hb + g * 132 + l2 * 8);
    float v[8];
#pragma unroll
    for (int k = 0; k < 8; ++k) v[k] = (float)hv[k];
    float s = 0.f, ssq = 0.f;
#pragma unroll
    for (int k = 0; k < 8; ++k) { s += v[k]; ssq += v[k] * v[k]; }
#pragma unroll
    for (int off = 1; off < 16; off <<= 1) {
        s += __shfl_xor(s, off, 64);
        ssq += __shfl_xor(ssq, off, 64);
    }
    const float mean = s * (1.0f / 128.0f);
    const float rstd = rsqrtf(ssq * (1.0f / 128.0f) - mean * mean + 1e-5f);
    float4* ob = (float4*)(outE + ((size_t)row * KNB + g) * HID + l2 * 8);
    const float4 g0 = *(const float4*)(lng + l2 * 8);
    const float4 g1 = *(const float4*)(lng + l2 * 8 + 4);
    const float4 b0 = *(const float4*)(lnb + l2 * 8);
    const float4 b1 = *(const float4*)(lnb + l2 * 8 + 4);
    float4 o0, o1;
    o0.x = (v[0] - mean) * rstd * g0.x + b0.x;
    o0.y = (v[1] - mean) * rstd * g0.y + b0.y;
    o0.z = (v[2] - mean) * rstd * g0.z + b0.z;
    o0.w = (v[3] - mean) * rstd * g0.w + b0.w;
    o1.x = (v[4] - mean) * rstd * g1.x + b1.x;
    o1.y = (v[5] - mean) * rstd * g1.y + b1.y;
    o1.z = (v[6] - mean) * rstd * g1.z + b1.z;
    o1.w = (v[7] - mean) * rstd * g1.w + b1.w;
    ob[0] = o0;
    ob[1] = o1;
}

__global__ __launch_bounds__(512, 4) void edge_kernel(
    const float* __restrict__ X,
    const int* __restrict__ Ridx, const int* __restrict__ Chain,
    const float* __restrict__ W_pos, const float* __restrict__ b_pos,
    const unsigned char* __restrict__ Wf8,
    const float* __restrict__ lng, const float* __restrict__ lnb,
    const float* __restrict__ eidx_f, float* __restrict__ outE) {
    const int tid = threadIdx.x;
    const int row0 = blockIdx.x * 8;
    const int b = row0 >> 11;                 // 2048 % 8 == 0: no batch straddle
    const int i0 = row0 & (LEN - 1);

    __shared__ __align__(16) unsigned char featF8[2][32 * FS];  // 32768 B
    __shared__ __align__(16) __bf16 hbA[32 * 132];              //  8448 B
    __shared__ __align__(16) __bf16 hbB[32 * 132];              //  8448 B
    __shared__ float natoms[8][32][15];                         // 15360 B
    __shared__ float iatoms[8][16];                             //   512 B
    __shared__ float wposL[16 * 66];                            //  4224 B
    __shared__ int jR[8][KNB], jC[8][KNB];                      //  2048 B
    __shared__ int riS[8], ciS[8];                              //    64 B

    const float* Xb = X + (size_t)b * LEN * 12;

    // --- W register residency (fp8, 26 regs/lane)
    const int w = tid >> 6, l = tid & 63, lr = l & 15, lg = l >> 4;
    long wreg[13];
    {
        const unsigned char* wb = Wf8 + (size_t)(w * 16 + lr) * 416 + lg * 8;
#pragma unroll
        for (int ks = 0; ks < 13; ++ks)
            wreg[ks] = *(const long*)(wb + ks * 32);
    }

    // --- prologue: wposL; ALL 8 rows' gathers in parallel
    for (int t = tid; t < 1056; t += 512)
        wposL[t] = W_pos[t] + b_pos[t / 66];
    if (tid < 256) {
        const int r = tid >> 5, e = tid & 31;
        const int j = (int)eidx_f[(size_t)(row0 + r) * KNB + e];
        jR[r][e] = Ridx[b * LEN + j];
        jC[r][e] = Chain[b * LEN + j];
        load_res_atoms(Xb + j * 12, &natoms[r][e][0]);
    } else if (tid < 264) {
        const int r = tid - 256;
        load_res_atoms(Xb + (size_t)(i0 + r) * 12, &iatoms[r][0]);
    } else if (tid < 272) {
        riS[tid - 264] = Ridx[b * LEN + i0 + (tid - 264)];
    } else if (tid < 280) {
        ciS[tid - 272] = Chain[b * LEN + i0 + (tid - 272)];
    }
    bar_lgkm();

    // features for rows 0,1
    compute_features(tid, riS[0], ciS[0], wposL, jR[0], jC[0],
                     natoms[0], iatoms[0], featF8[0]);
    compute_features(tid, riS[1], ciS[1], wposL, jR[1], jC[1],
                     natoms[1], iatoms[1], featF8[1]);
    bar_lgkm();

    for (int it = 0; it < 4; ++it) {
        const int ra = row0 + 2 * it, rb = ra + 1;

        // === region B: GEMM both rows (4 indep chains) + bf16 scatter ===
        f32x4 accA0 = {0.f, 0.f, 0.f, 0.f}, accA1 = accA0;
        f32x4 accB0 = accA0, accB1 = accA0;
        gemm_row(featF8[0], wreg, lr, lg, accA0, accA1);
        gemm_row(featF8[1], wreg, lr, lg, accB0, accB1);
#pragma unroll
        for (int rr = 0; rr < 4; ++rr) {
            const int ch = w * 16 + lr;
            hbA[(lg * 4 + rr) * 132 + ch]      = (__bf16)accA0[rr];
            hbA[(16 + lg * 4 + rr) * 132 + ch] = (__bf16)accA1[rr];
            hbB[(lg * 4 + rr) * 132 + ch]      = (__bf16)accB0[rr];
            hbB[(16 + lg * 4 + rr) * 132 + ch] = (__bf16)accB1[rr];
        }
        bar_lgkm();

        // === region C: LN both rows + features(next 2 rows) ===
        ln_store(hbA, ra, tid, lng, lnb, outE);
        ln_store(hbB, rb, tid, lng, lnb, outE);
        if (it < 3) {
            const int na = 2 * it + 2, nb = 2 * it + 3;
            compute_features(tid, riS[na], ciS[na], wposL, jR[na], jC[na],
                             natoms[na], iatoms[na], featF8[0]);
            compute_features(tid, riS[nb], ciS[nb], wposL, jR[nb], jC[nb],
                             natoms[nb], iatoms[nb], featF8[1]);
        }
        bar_lgkm();
    }
}

extern "C" void kernel_launch(void* const* d_in, const int* in_sizes, int n_in,
                              void* d_out, int out_size, void* d_ws, size_t ws_size,
                              hipStream_t stream) {
    const float* X      = (const float*)d_in[0];
    const float* mask   = (const float*)d_in[1];
    const int*   Ridx   = (const int*)d_in[2];
    const int*   Chain  = (const int*)d_in[3];
    const float* W_pos  = (const float*)d_in[4];
    const float* b_pos  = (const float*)d_in[5];
    const float* W_edge = (const float*)d_in[6];
    const float* lng    = (const float*)d_in[7];
    const float* lnb    = (const float*)d_in[8];

    float* out  = (float*)d_out;
    float* eidx = out;                           // B*L*K floats (exact ints)
    float* E    = out + (size_t)2 * LEN * KNB;   // B*L*K*HID floats

    float4* CAm = (float4*)d_ws;                                  // 64 KiB
    unsigned char* Wf8 = (unsigned char*)d_ws + 2 * LEN * 16;     // 52 KiB

    const int nrow = 2 * LEN;
    prep_kernel<<<52, 256, 0, stream>>>(X, mask, W_edge, CAm, (int*)Wf8);
    topk_kernel<<<nrow, 256, 0, stream>>>(CAm, eidx);
    edge_kernel<<<nrow / 8, 512, 0, stream>>>(X, Ridx, Chain, W_pos, b_pos, Wf8,
                                              lng, lnb, eidx, E);
}

// Round 13
// 59.947 us; speedup vs baseline: 1.0382x; 1.0382x over previous
//
#include <hip/hip_runtime.h>
#include <hip/hip_bf16.h>

#define LEN   2048
#define KNB   32
#define HID   128
#define FS    512   // fp8 bytes/feature-row: 32 16B-blocks, XOR-swizzle closed

typedef unsigned long long ull;
typedef unsigned int uint32;
typedef float f32x4  __attribute__((ext_vector_type(4)));
typedef float f32x16 __attribute__((ext_vector_type(16)));

// LDS-only barrier: output stores (vmcnt) stay in flight across rows.
__device__ __forceinline__ void bar_lgkm() {
    asm volatile("s_waitcnt lgkmcnt(0)" ::: "memory");
    __builtin_amdgcn_s_barrier();
    asm volatile("" ::: "memory");
}

// ---------------------------------------------------------------------------
// Kernel 0: prep — pack CA+mask as float4; convert W_edge f32 -> fp8 e4m3.
// ---------------------------------------------------------------------------
__global__ __launch_bounds__(256) void prep_kernel(
    const float* __restrict__ X, const float* __restrict__ mask,
    const float* __restrict__ W_edge,
    float4* __restrict__ CAm, int* __restrict__ Wf8) {
    const int t = blockIdx.x * 256 + threadIdx.x;
    if (t < 2 * LEN) {
        const float* p = X + (size_t)t * 12;
        CAm[t] = make_float4(p[3], p[4], p[5],
                             __fmul_rn(__fsub_rn(1.0f, mask[t]), 1000000.0f));
    }
    if (t < 13312) {
        const float4 w = ((const float4*)W_edge)[t];
        int r = __builtin_amdgcn_cvt_pk_fp8_f32(w.x, w.y, 0, false);
        r = __builtin_amdgcn_cvt_pk_fp8_f32(w.z, w.w, r, true);
        Wf8[t] = r;
    }
}

// ---------------------------------------------------------------------------
// Kernel 1: exact top-K=32 via histogram-select (proven ~10us standalone).
// ---------------------------------------------------------------------------
__global__ __launch_bounds__(256) void topk_kernel(
    const float4* __restrict__ CAm, float* __restrict__ eidx_out) {
    const int row = blockIdx.x;
    const int b = row >> 11;
    const int i = row & (LEN - 1);
    const int tid = threadIdx.x;

    __shared__ int hist[512];
    __shared__ ull cand[LEN];
    __shared__ int candcnt;
    __shared__ int selB;

    const float4* C = CAm + (size_t)b * LEN;
    const float4 ci = C[i];

    uint32 d2b[8];
#pragma unroll
    for (int q = 0; q < 8; ++q) {
        const float4 cj = C[q * 256 + tid];
        float dx = __fsub_rn(ci.x, cj.x);
        float dy = __fsub_rn(ci.y, cj.y);
        float dz = __fsub_rn(ci.z, cj.z);
        float d2 = __fadd_rn(__fadd_rn(__fmul_rn(dx, dx), __fmul_rn(dy, dy)),
                             __fmul_rn(dz, dz));
        d2 = __fadd_rn(d2, cj.w);
        d2b[q] = __float_as_uint(d2);
    }

    hist[tid] = 0; hist[tid + 256] = 0;
    if (tid == 0) candcnt = 0;
    __syncthreads();
#pragma unroll
    for (int q = 0; q < 8; ++q) atomicAdd(&hist[d2b[q] >> 22], 1);
    __syncthreads();

    if (tid < 64) {
        int loc[8];
        int s = 0;
#pragma unroll
        for (int t = 0; t < 8; ++t) { loc[t] = hist[tid * 8 + t]; s += loc[t]; }
        int incl = s;
#pragma unroll
        for (int off = 1; off < 64; off <<= 1) {
            int o = __shfl_up(incl, off, 64);
            if (tid >= off) incl += o;
        }
        const int excl = incl - s;
        if (excl < KNB && incl >= KNB) {
            int c = excl;
#pragma unroll
            for (int t = 0; t < 8; ++t) {
                int c2 = c + loc[t];
                if (c < KNB && c2 >= KNB) selB = tid * 8 + t;
                c = c2;
            }
        }
    }
    __syncthreads();
    const uint32 B = (uint32)selB;

#pragma unroll
    for (int q = 0; q < 8; ++q) {
        if ((d2b[q] >> 22) <= B) {
            int p = atomicAdd(&candcnt, 1);
            cand[p] = (((ull)d2b[q]) << 32) | (uint32)(q * 256 + tid);
        }
    }
    __syncthreads();
    const int M = candcnt;

    for (int c = tid; c < M; c += 256) {
        const ull k = cand[c];
        int r = 0;
        for (int m = 0; m < M; ++m) r += (cand[m] < k);
        if (r < KNB)
            eidx_out[(size_t)row * KNB + r] = (float)(uint32)(k & 0xFFFFFFFFull);
    }
}

// ---------------------------------------------------------------------------
// Kernel 2: 8 rows/block, 512 thr, 512 blocks. 32x32x16 fp8 MFMA:
// D[ch][edge] -> lane holds 16 channels of ONE edge (col=lane&31) ->
// LN directly from acc (1 shfl + 1KB pS/pQ cross-wave buffer), no hbuf.
// Waves 0-3: row A x 32-ch groups; waves 4-7: row B. W reg-resident (52).
// ---------------------------------------------------------------------------
__device__ __forceinline__ void load_res_atoms(const float* __restrict__ p, float* dst) {
    const float Nx = p[0], Ny = p[1], Nz = p[2];
    const float Ax = p[3], Ay = p[4], Az = p[5];
    const float Cx = p[6], Cy = p[7], Cz = p[8];
    const float Ox = p[9], Oy = p[10], Oz = p[11];
    const float bx = Ax - Nx, by = Ay - Ny, bz = Az - Nz;
    const float cx = Cx - Ax, cy = Cy - Ay, cz = Cz - Az;
    const float axv = by * cz - bz * cy;
    const float ayv = bz * cx - bx * cz;
    const float azv = bx * cy - by * cx;
    dst[0] = Nx;  dst[1] = Ny;  dst[2] = Nz;
    dst[3] = Ax;  dst[4] = Ay;  dst[5] = Az;
    dst[6] = Cx;  dst[7] = Cy;  dst[8] = Cz;
    dst[9] = Ox;  dst[10] = Oy; dst[11] = Oz;
    dst[12] = -0.58273431f * axv + 0.56802827f * bx + -0.54067466f * cx + Ax;
    dst[13] = -0.58273431f * ayv + 0.56802827f * by + -0.54067466f * cy + Ay;
    dst[14] = -0.58273431f * azv + 0.56802827f * bz + -0.54067466f * cz + Az;
}

__device__ __forceinline__ int pk4(float a, float b, float c, float d) {
    int r = __builtin_amdgcn_cvt_pk_fp8_f32(a, b, 0, false);
    return __builtin_amdgcn_cvt_pk_fp8_f32(c, d, r, true);
}

// chain constants exp(-1.1377778 * (2j+1)), j = 0..3
#define E1  3.2053337e-1f
#define E3  3.2931300e-2f
#define E5  3.3834001e-3f
#define E7  3.4760500e-4f

__device__ __forceinline__ void compute_features(
    int tid, int Ri, int Ci,
    const float* __restrict__ wposL,
    const int* jR, const int* jC,
    const float (*natoms)[15], const float* iatoms,
    unsigned char* featF8) {
    {
        const int e = tid >> 4, p = tid & 15;
        const int drel = jR[e] - Ri;
        const int same = (jC[e] == Ci);
        int dc = drel + 32;
        dc = dc < 0 ? 0 : (dc > 64 ? 64 : dc);
        const int df = same ? dc : 65;
        const float v = wposL[p * 66 + df];
        const int pb = __builtin_amdgcn_cvt_pk_fp8_f32(v, 0.0f, 0, false);
        featF8[e * FS + ((e & 7) << 4) + p] = (unsigned char)(pb & 0xFF);
    }
#pragma unroll
    for (int it = 0; it < 2; ++it) {
        const int task = tid + it * 512;
        if (task < 800) {
            const int mn = task >> 5, e = task & 31;
            const int m = mn / 5, n = mn - m * 5;
            const float ax = iatoms[m * 3 + 0];
            const float ay = iatoms[m * 3 + 1];
            const float az = iatoms[m * 3 + 2];
            const float* na = &natoms[e][n * 3];
            const float dx = ax - na[0], dy = ay - na[1], dz = az - na[2];
            const float D = sqrtf(dx * dx + dy * dy + dz * dz + 1e-6f);
            const float Dc = fminf(D, 40.0f);
            const float v4 = Dc - 7.3333333f;
            const float A4  = __expf(-0.64f * v4 * v4);
            const float C4  = __expf(1.7066667f * v4);
            const float Ci4 = 1.0f / C4;
            int4 w4;
            {
                const float f3 = A4 * Ci4 * E1;
                const float f2 = f3 * Ci4 * E3;
                const float f1 = f2 * Ci4 * E5;
                const float f0 = f1 * Ci4 * E7;
                w4.x = pk4(f0, f1, f2, f3);
            }
            {
                const float f5 = A4 * C4 * E1;
                const float f6 = f5 * C4 * E3;
                const float f7 = f6 * C4 * E5;
                w4.y = pk4(A4, f5, f6, f7);
            }
            const float v12 = Dc - 18.0f;
            const float A12  = __expf(-0.64f * v12 * v12);
            const float C12  = C4 * 1.24140e-8f;
            const float Ci12 = Ci4 * 8.05543e7f;
            {
                const float f11 = A12 * Ci12 * E1;
                const float f10 = f11 * Ci12 * E3;
                const float f9  = f10 * Ci12 * E5;
                const float f8  = f9  * Ci12 * E7;
                w4.z = pk4(f8, f9, f10, f11);
            }
            {
                const float f13 = A12 * C12 * E1;
                const float f14 = f13 * C12 * E3;
                const float f15 = f14 * C12 * E5;
                w4.w = pk4(A12, f13, f14, f15);
            }
            *(int4*)(featF8 + e * FS + (((1 + mn) ^ (e & 7)) << 4)) = w4;
        }
    }
}

__global__ __launch_bounds__(512, 4) void edge_kernel(
    const float* __restrict__ X,
    const int* __restrict__ Ridx, const int* __restrict__ Chain,
    const float* __restrict__ W_pos, const float* __restrict__ b_pos,
    const unsigned char* __restrict__ Wf8,
    const float* __restrict__ lng, const float* __restrict__ lnb,
    const float* __restrict__ eidx_f, float* __restrict__ outE) {
    const int tid = threadIdx.x;
    const int row0 = blockIdx.x * 8;
    const int b = row0 >> 11;                 // 2048 % 8 == 0: no batch straddle
    const int i0 = row0 & (LEN - 1);

    __shared__ __align__(16) unsigned char featF8[2][32 * FS];  // 32768 B
    __shared__ float natoms[8][32][15];                         // 15360 B
    __shared__ float iatoms[8][16];                             //   512 B
    __shared__ float wposL[16 * 66];                            //  4224 B
    __shared__ __align__(16) float pS[2][32][4], pQ[2][32][4];  //  2048 B
    __shared__ float gbuf[HID], bbuf[HID];                      //  1024 B
    __shared__ int jR[8][KNB], jC[8][KNB];                      //  2048 B
    __shared__ int riS[8], ciS[8];                              //    64 B

    const float* Xb = X + (size_t)b * LEN * 12;

    // --- lane geometry: wave w; rowsel = w>>2 (A/B), cg = w&3 (32-ch group);
    //     e32 = lane&31 (edge for B/D; channel-within-group for A); hi = lane>>5.
    const int w = tid >> 6, l = tid & 63;
    const int rowsel = w >> 2, cg = w & 3;
    const int e32 = l & 31, hi = l >> 5;

    // --- W register residency: lane holds W[cg*32+e32][k], 8 consecutive k
    //     per K-step (k-half by hi). 26 steps x 8B = 52 VGPRs.
    long wreg[26];
    {
        const unsigned char* wb = Wf8 + (size_t)(cg * 32 + e32) * 416 + hi * 8;
#pragma unroll
        for (int ks = 0; ks < 26; ++ks)
            wreg[ks] = *(const long*)(wb + ks * 16);
    }

    // --- prologue: wposL; gamma/beta; ALL 8 rows' gathers in parallel
    for (int t = tid; t < 1056; t += 512)
        wposL[t] = W_pos[t] + b_pos[t / 66];
    if (tid < 256) {
        const int r = tid >> 5, e = tid & 31;
        const int j = (int)eidx_f[(size_t)(row0 + r) * KNB + e];
        jR[r][e] = Ridx[b * LEN + j];
        jC[r][e] = Chain[b * LEN + j];
        load_res_atoms(Xb + j * 12, &natoms[r][e][0]);
    } else if (tid < 264) {
        const int r = tid - 256;
        load_res_atoms(Xb + (size_t)(i0 + r) * 12, &iatoms[r][0]);
    } else if (tid < 272) {
        riS[tid - 264] = Ridx[b * LEN + i0 + (tid - 264)];
    } else if (tid < 280) {
        ciS[tid - 272] = Chain[b * LEN + i0 + (tid - 272)];
    } else if (tid >= 384) {
        const int t2 = tid - 384;
        gbuf[t2] = lng[t2];
        bbuf[t2] = lnb[t2];
    }
    bar_lgkm();

    // features for rows 0,1
    compute_features(tid, riS[0], ciS[0], wposL, jR[0], jC[0],
                     natoms[0], iatoms[0], featF8[0]);
    compute_features(tid, riS[1], ciS[1], wposL, jR[1], jC[1],
                     natoms[1], iatoms[1], featF8[1]);
    bar_lgkm();

    for (int it = 0; it < 4; ++it) {
        const int myrow = row0 + 2 * it + rowsel;

        // === region B: GEMM (own row, 26 x 32x32x16 MFMA) + partials ===
        f32x16 acc = {0.f, 0.f, 0.f, 0.f, 0.f, 0.f, 0.f, 0.f,
                      0.f, 0.f, 0.f, 0.f, 0.f, 0.f, 0.f, 0.f};
        {
            const unsigned char* fb = featF8[rowsel] + e32 * FS + hi * 8;
            const int sw = e32 & 7;
#pragma unroll
            for (int ks = 0; ks < 26; ++ks) {
                const long a = *(const long*)(fb + ((ks ^ sw) << 4));
                acc = __builtin_amdgcn_mfma_f32_32x32x16_fp8_fp8(wreg[ks], a, acc, 0, 0, 0);
            }
        }
        {
            float s = 0.f, q = 0.f;
#pragma unroll
            for (int r = 0; r < 16; ++r) { s += acc[r]; q += acc[r] * acc[r]; }
            s += __shfl_xor(s, 32, 64);
            q += __shfl_xor(q, 32, 64);
            if (hi == 0) {
                pS[rowsel][e32][cg] = s;
                pQ[rowsel][e32][cg] = q;
            }
        }
        bar_lgkm();

        // === region C: LN finish from acc + store; features(next 2 rows) ===
        {
            const float4 ps = *(const float4*)&pS[rowsel][e32][0];
            const float4 pq = *(const float4*)&pQ[rowsel][e32][0];
            const float s = ps.x + ps.y + ps.z + ps.w;
            const float q = pq.x + pq.y + pq.z + pq.w;
            const float mean = s * (1.0f / 128.0f);
            const float rstd = rsqrtf(q * (1.0f / 128.0f) - mean * mean + 1e-5f);
            const int cb = cg * 32 + hi * 4;
            float* orow = outE + ((size_t)myrow * KNB + e32) * HID + cb;
#pragma unroll
            for (int j = 0; j < 4; ++j) {
                const float4 gg = *(const float4*)&gbuf[cb + 8 * j];
                const float4 bb = *(const float4*)&bbuf[cb + 8 * j];
                float4 o;
                o.x = (acc[4 * j + 0] - mean) * rstd * gg.x + bb.x;
                o.y = (acc[4 * j + 1] - mean) * rstd * gg.y + bb.y;
                o.z = (acc[4 * j + 2] - mean) * rstd * gg.z + bb.z;
                o.w = (acc[4 * j + 3] - mean) * rstd * gg.w + bb.w;
                *(float4*)(orow + 8 * j) = o;
            }
        }
        if (it < 3) {
            const int na = 2 * it + 2, nb = 2 * it + 3;
            compute_features(tid, riS[na], ciS[na], wposL, jR[na], jC[na],
                             natoms[na], iatoms[na], featF8[0]);
            compute_features(tid, riS[nb], ciS[nb], wposL, jR[nb], jC[nb],
                             natoms[nb], iatoms[nb], featF8[1]);
        }
        bar_lgkm();
    }
}

extern "C" void kernel_launch(void* const* d_in, const int* in_sizes, int n_in,
                              void* d_out, int out_size, void* d_ws, size_t ws_size,
                              hipStream_t stream) {
    const float* X      = (const float*)d_in[0];
    const float* mask   = (const float*)d_in[1];
    const int*   Ridx   = (const int*)d_in[2];
    const int*   Chain  = (const int*)d_in[3];
    const float* W_pos  = (const float*)d_in[4];
    const float* b_pos  = (const float*)d_in[5];
    const float* W_edge = (const float*)d_in[6];
    const float* lng    = (const float*)d_in[7];
    const float* lnb    = (const float*)d_in[8];

    float* out  = (float*)d_out;
    float* eidx = out;                           // B*L*K floats (exact ints)
    float* E    = out + (size_t)2 * LEN * KNB;   // B*L*K*HID floats

    float4* CAm = (float4*)d_ws;                                  // 64 KiB
    unsigned char* Wf8 = (unsigned char*)d_ws + 2 * LEN * 16;     // 52 KiB

    const int nrow = 2 * LEN;
    prep_kernel<<<52, 256, 0, stream>>>(X, mask, W_edge, CAm, (int*)Wf8);
    topk_kernel<<<nrow, 256, 0, stream>>>(CAm, eidx);
    edge_kernel<<<nrow / 8, 512, 0, stream>>>(X, Ridx, Chain, W_pos, b_pos, Wf8,
                                              lng, lnb, eidx, E);
}

// Round 14
// 54.705 us; speedup vs baseline: 1.1376x; 1.0958x over previous
//
#include <hip/hip_runtime.h>
#include <hip/hip_bf16.h>

#define LEN   2048
#define KNB   32
#define HID   128
#define FS    520   // fp8 bytes/feature-row; 130 dw % 32 = 2 -> b64 reads at bank floor

typedef unsigned long long ull;
typedef unsigned int uint32;
typedef float f32x4  __attribute__((ext_vector_type(4)));
typedef float f32x16 __attribute__((ext_vector_type(16)));

// LDS-only barrier: output stores (vmcnt) stay in flight across rows.
__device__ __forceinline__ void bar_lgkm() {
    asm volatile("s_waitcnt lgkmcnt(0)" ::: "memory");
    __builtin_amdgcn_s_barrier();
    asm volatile("" ::: "memory");
}

// ---------------------------------------------------------------------------
// Kernel 1: blocks 0..4095 — exact top-K=32 via histogram-select, with the
// mask penalty computed inline (bit-exact same rn-op sequence as before).
// Blocks 4096..4147 — convert W_edge f32 -> fp8 e4m3 (was prep_kernel).
// ---------------------------------------------------------------------------
__global__ __launch_bounds__(256) void topk_kernel(
    const float* __restrict__ X, const float* __restrict__ mask,
    const float* __restrict__ W_edge, int* __restrict__ Wf8,
    float* __restrict__ eidx_out) {
    const int bid = blockIdx.x;
    const int tid = threadIdx.x;

    if (bid >= 2 * LEN) {    // W-convert tail blocks
        const int t = (bid - 2 * LEN) * 256 + tid;
        if (t < 13312) {
            const float4 w = ((const float4*)W_edge)[t];
            int r = __builtin_amdgcn_cvt_pk_fp8_f32(w.x, w.y, 0, false);
            r = __builtin_amdgcn_cvt_pk_fp8_f32(w.z, w.w, r, true);
            Wf8[t] = r;
        }
        return;
    }

    const int row = bid;
    const int b = row >> 11;
    const int i = row & (LEN - 1);

    __shared__ int hist[512];
    __shared__ ull cand[LEN];
    __shared__ int candcnt;
    __shared__ int selB;

    const float* Xb = X + (size_t)b * LEN * 12;
    const float* mb = mask + (size_t)b * LEN;
    const float cax = Xb[i * 12 + 3];
    const float cay = Xb[i * 12 + 4];
    const float caz = Xb[i * 12 + 5];

    uint32 d2b[8];
#pragma unroll
    for (int q = 0; q < 8; ++q) {
        const int j = q * 256 + tid;
        float dx = __fsub_rn(cax, Xb[j * 12 + 3]);
        float dy = __fsub_rn(cay, Xb[j * 12 + 4]);
        float dz = __fsub_rn(caz, Xb[j * 12 + 5]);
        float d2 = __fadd_rn(__fadd_rn(__fmul_rn(dx, dx), __fmul_rn(dy, dy)),
                             __fmul_rn(dz, dz));
        d2 = __fadd_rn(d2, __fmul_rn(__fsub_rn(1.0f, mb[j]), 1000000.0f));
        d2b[q] = __float_as_uint(d2);
    }

    hist[tid] = 0; hist[tid + 256] = 0;
    if (tid == 0) candcnt = 0;
    __syncthreads();
#pragma unroll
    for (int q = 0; q < 8; ++q) atomicAdd(&hist[d2b[q] >> 22], 1);
    __syncthreads();

    if (tid < 64) {
        int loc[8];
        int s = 0;
#pragma unroll
        for (int t = 0; t < 8; ++t) { loc[t] = hist[tid * 8 + t]; s += loc[t]; }
        int incl = s;
#pragma unroll
        for (int off = 1; off < 64; off <<= 1) {
            int o = __shfl_up(incl, off, 64);
            if (tid >= off) incl += o;
        }
        const int excl = incl - s;
        if (excl < KNB && incl >= KNB) {
            int c = excl;
#pragma unroll
            for (int t = 0; t < 8; ++t) {
                int c2 = c + loc[t];
                if (c < KNB && c2 >= KNB) selB = tid * 8 + t;
                c = c2;
            }
        }
    }
    __syncthreads();
    const uint32 B = (uint32)selB;

#pragma unroll
    for (int q = 0; q < 8; ++q) {
        if ((d2b[q] >> 22) <= B) {
            int p = atomicAdd(&candcnt, 1);
            cand[p] = (((ull)d2b[q]) << 32) | (uint32)(q * 256 + tid);
        }
    }
    __syncthreads();
    const int M = candcnt;

    for (int c = tid; c < M; c += 256) {
        const ull k = cand[c];
        int r = 0;
        for (int m = 0; m < M; ++m) r += (cand[m] < k);
        if (r < KNB)
            eidx_out[(size_t)row * KNB + r] = (float)(uint32)(k & 0xFFFFFFFFull);
    }
}

// ---------------------------------------------------------------------------
// Kernel 2: 8 rows/block, 512 thr, 512 blocks. 32x32x16 fp8 MFMA, LN from
// accumulators (no hbuf). FS=520: b64 feature stores + A-reads at bank floor,
// no XOR swizzle. W register-resident (52 VGPR). lgkm-only barriers.
// ---------------------------------------------------------------------------
__device__ __forceinline__ void load_res_atoms(const float* __restrict__ p, float* dst) {
    const float Nx = p[0], Ny = p[1], Nz = p[2];
    const float Ax = p[3], Ay = p[4], Az = p[5];
    const float Cx = p[6], Cy = p[7], Cz = p[8];
    const float Ox = p[9], Oy = p[10], Oz = p[11];
    const float bx = Ax - Nx, by = Ay - Ny, bz = Az - Nz;
    const float cx = Cx - Ax, cy = Cy - Ay, cz = Cz - Az;
    const float axv = by * cz - bz * cy;
    const float ayv = bz * cx - bx * cz;
    const float azv = bx * cy - by * cx;
    dst[0] = Nx;  dst[1] = Ny;  dst[2] = Nz;
    dst[3] = Ax;  dst[4] = Ay;  dst[5] = Az;
    dst[6] = Cx;  dst[7] = Cy;  dst[8] = Cz;
    dst[9] = Ox;  dst[10] = Oy; dst[11] = Oz;
    dst[12] = -0.58273431f * axv + 0.56802827f * bx + -0.54067466f * cx + Ax;
    dst[13] = -0.58273431f * ayv + 0.56802827f * by + -0.54067466f * cy + Ay;
    dst[14] = -0.58273431f * azv + 0.56802827f * bz + -0.54067466f * cz + Az;
}

__device__ __forceinline__ int pk4(float a, float b, float c, float d) {
    int r = __builtin_amdgcn_cvt_pk_fp8_f32(a, b, 0, false);
    return __builtin_amdgcn_cvt_pk_fp8_f32(c, d, r, true);
}

// chain constants exp(-1.1377778 * (2j+1)), j = 0..3
#define E1  3.2053337e-1f
#define E3  3.2931300e-2f
#define E5  3.3834001e-3f
#define E7  3.4760500e-4f

__device__ __forceinline__ void compute_features(
    int tid, int Ri, int Ci,
    const float* __restrict__ wposL,
    const int* jR, const int* jC,
    const float (*natoms)[15], const float* iatoms,
    unsigned char* featF8) {
    {
        const int e = tid >> 4, p = tid & 15;
        const int drel = jR[e] - Ri;
        const int same = (jC[e] == Ci);
        int dc = drel + 32;
        dc = dc < 0 ? 0 : (dc > 64 ? 64 : dc);
        const int df = same ? dc : 65;
        const float v = wposL[p * 66 + df];
        const int pb = __builtin_amdgcn_cvt_pk_fp8_f32(v, 0.0f, 0, false);
        featF8[e * FS + p] = (unsigned char)(pb & 0xFF);
    }
#pragma unroll
    for (int it = 0; it < 2; ++it) {
        const int task = tid + it * 512;
        if (task < 800) {
            const int mn = task >> 5, e = task & 31;
            const int m = mn / 5, n = mn - m * 5;
            const float ax = iatoms[m * 3 + 0];
            const float ay = iatoms[m * 3 + 1];
            const float az = iatoms[m * 3 + 2];
            const float* na = &natoms[e][n * 3];
            const float dx = ax - na[0], dy = ay - na[1], dz = az - na[2];
            const float D = sqrtf(dx * dx + dy * dy + dz * dz + 1e-6f);
            const float Dc = fminf(D, 40.0f);
            const float v4 = Dc - 7.3333333f;
            const float A4  = __expf(-0.64f * v4 * v4);
            const float C4  = __expf(1.7066667f * v4);
            const float Ci4 = 1.0f / C4;
            ull lo, hi2;
            {
                const float f3 = A4 * Ci4 * E1;
                const float f2 = f3 * Ci4 * E3;
                const float f1 = f2 * Ci4 * E5;
                const float f0 = f1 * Ci4 * E7;
                const float f5 = A4 * C4 * E1;
                const float f6 = f5 * C4 * E3;
                const float f7 = f6 * C4 * E5;
                lo = (uint32)pk4(f0, f1, f2, f3)
                   | ((ull)(uint32)pk4(A4, f5, f6, f7) << 32);
            }
            const float v12 = Dc - 18.0f;
            const float A12  = __expf(-0.64f * v12 * v12);
            const float C12  = C4 * 1.24140e-8f;
            const float Ci12 = Ci4 * 8.05543e7f;
            {
                const float f11 = A12 * Ci12 * E1;
                const float f10 = f11 * Ci12 * E3;
                const float f9  = f10 * Ci12 * E5;
                const float f8  = f9  * Ci12 * E7;
                const float f13 = A12 * C12 * E1;
                const float f14 = f13 * C12 * E3;
                const float f15 = f14 * C12 * E5;
                hi2 = (uint32)pk4(f8, f9, f10, f11)
                    | ((ull)(uint32)pk4(A12, f13, f14, f15) << 32);
            }
            *(ull*)(featF8 + e * FS + 16 + mn * 16)     = lo;
            *(ull*)(featF8 + e * FS + 16 + mn * 16 + 8) = hi2;
        }
    }
}

__global__ __launch_bounds__(512, 4) void edge_kernel(
    const float* __restrict__ X,
    const int* __restrict__ Ridx, const int* __restrict__ Chain,
    const float* __restrict__ W_pos, const float* __restrict__ b_pos,
    const unsigned char* __restrict__ Wf8,
    const float* __restrict__ lng, const float* __restrict__ lnb,
    const float* __restrict__ eidx_f, float* __restrict__ outE) {
    const int tid = threadIdx.x;
    const int row0 = blockIdx.x * 8;
    const int b = row0 >> 11;                 // 2048 % 8 == 0: no batch straddle
    const int i0 = row0 & (LEN - 1);

    __shared__ __align__(16) unsigned char featF8[2][32 * FS];  // 33280 B
    __shared__ float natoms[8][32][15];                         // 15360 B
    __shared__ float iatoms[8][16];                             //   512 B
    __shared__ float wposL[16 * 66];                            //  4224 B
    __shared__ __align__(16) float pS[2][32][4], pQ[2][32][4];  //  2048 B
    __shared__ float gbuf[HID], bbuf[HID];                      //  1024 B
    __shared__ int jR[8][KNB], jC[8][KNB];                      //  2048 B
    __shared__ int riS[8], ciS[8];                              //    64 B

    const float* Xb = X + (size_t)b * LEN * 12;

    // --- lane geometry: rowsel = w>>2 (A/B row), cg = w&3 (32-ch group);
    //     e32 = lane&31; hi = lane>>5 (K-half).
    const int w = tid >> 6, l = tid & 63;
    const int rowsel = w >> 2, cg = w & 3;
    const int e32 = l & 31, hi = l >> 5;

    // --- W register residency: W[cg*32+e32][k], 26 steps x 8B = 52 VGPRs.
    long wreg[26];
    {
        const unsigned char* wb = Wf8 + (size_t)(cg * 32 + e32) * 416 + hi * 8;
#pragma unroll
        for (int ks = 0; ks < 26; ++ks)
            wreg[ks] = *(const long*)(wb + ks * 16);
    }

    // --- prologue: wposL; gamma/beta; ALL 8 rows' gathers in parallel
    for (int t = tid; t < 1056; t += 512)
        wposL[t] = W_pos[t] + b_pos[t / 66];
    if (tid < 256) {
        const int r = tid >> 5, e = tid & 31;
        const int j = (int)eidx_f[(size_t)(row0 + r) * KNB + e];
        jR[r][e] = Ridx[b * LEN + j];
        jC[r][e] = Chain[b * LEN + j];
        load_res_atoms(Xb + j * 12, &natoms[r][e][0]);
    } else if (tid < 264) {
        const int r = tid - 256;
        load_res_atoms(Xb + (size_t)(i0 + r) * 12, &iatoms[r][0]);
    } else if (tid < 272) {
        riS[tid - 264] = Ridx[b * LEN + i0 + (tid - 264)];
    } else if (tid < 280) {
        ciS[tid - 272] = Chain[b * LEN + i0 + (tid - 272)];
    } else if (tid >= 384) {
        const int t2 = tid - 384;
        gbuf[t2] = lng[t2];
        bbuf[t2] = lnb[t2];
    }
    bar_lgkm();

    // features for rows 0,1
    compute_features(tid, riS[0], ciS[0], wposL, jR[0], jC[0],
                     natoms[0], iatoms[0], featF8[0]);
    compute_features(tid, riS[1], ciS[1], wposL, jR[1], jC[1],
                     natoms[1], iatoms[1], featF8[1]);
    bar_lgkm();

    for (int it = 0; it < 4; ++it) {
        const int myrow = row0 + 2 * it + rowsel;

        // === region B: GEMM (own row, 26 x 32x32x16 MFMA) + partials ===
        f32x16 acc = {0.f, 0.f, 0.f, 0.f, 0.f, 0.f, 0.f, 0.f,
                      0.f, 0.f, 0.f, 0.f, 0.f, 0.f, 0.f, 0.f};
        {
            const unsigned char* fb = featF8[rowsel] + e32 * FS + hi * 8;
#pragma unroll
            for (int ks = 0; ks < 26; ++ks) {
                const long a = *(const long*)(fb + ks * 16);
                acc = __builtin_amdgcn_mfma_f32_32x32x16_fp8_fp8(wreg[ks], a, acc, 0, 0, 0);
            }
        }
        {
            float s = 0.f, q = 0.f;
#pragma unroll
            for (int r = 0; r < 16; ++r) { s += acc[r]; q += acc[r] * acc[r]; }
            s += __shfl_xor(s, 32, 64);
            q += __shfl_xor(q, 32, 64);
            if (hi == 0) {
                pS[rowsel][e32][cg] = s;
                pQ[rowsel][e32][cg] = q;
            }
        }
        bar_lgkm();

        // === region C: LN finish from acc + store; features(next 2 rows) ===
        {
            const float4 ps = *(const float4*)&pS[rowsel][e32][0];
            const float4 pq = *(const float4*)&pQ[rowsel][e32][0];
            const float s = ps.x + ps.y + ps.z + ps.w;
            const float q = pq.x + pq.y + pq.z + pq.w;
            const float mean = s * (1.0f / 128.0f);
            const float rstd = rsqrtf(q * (1.0f / 128.0f) - mean * mean + 1e-5f);
            const int cb = cg * 32 + hi * 4;
            float* orow = outE + ((size_t)myrow * KNB + e32) * HID + cb;
#pragma unroll
            for (int j = 0; j < 4; ++j) {
                const float4 gg = *(const float4*)&gbuf[cb + 8 * j];
                const float4 bb = *(const float4*)&bbuf[cb + 8 * j];
                float4 o;
                o.x = (acc[4 * j + 0] - mean) * rstd * gg.x + bb.x;
                o.y = (acc[4 * j + 1] - mean) * rstd * gg.y + bb.y;
                o.z = (acc[4 * j + 2] - mean) * rstd * gg.z + bb.z;
                o.w = (acc[4 * j + 3] - mean) * rstd * gg.w + bb.w;
                *(float4*)(orow + 8 * j) = o;
            }
        }
        if (it < 3) {
            const int na = 2 * it + 2, nb = 2 * it + 3;
            compute_features(tid, riS[na], ciS[na], wposL, jR[na], jC[na],
                             natoms[na], iatoms[na], featF8[0]);
            compute_features(tid, riS[nb], ciS[nb], wposL, jR[nb], jC[nb],
                             natoms[nb], iatoms[nb], featF8[1]);
        }
        bar_lgkm();
    }
}

extern "C" void kernel_launch(void* const* d_in, const int* in_sizes, int n_in,
                              void* d_out, int out_size, void* d_ws, size_t ws_size,
                              hipStream_t stream) {
    const float* X      = (const float*)d_in[0];
    const float* mask   = (const float*)d_in[1];
    const int*   Ridx   = (const int*)d_in[2];
    const int*   Chain  = (const int*)d_in[3];
    const float* W_pos  = (const float*)d_in[4];
    const float* b_pos  = (const float*)d_in[5];
    const float* W_edge = (const float*)d_in[6];
    const float* lng    = (const float*)d_in[7];
    const float* lnb    = (const float*)d_in[8];

    float* out  = (float*)d_out;
    float* eidx = out;                           // B*L*K floats (exact ints)
    float* E    = out + (size_t)2 * LEN * KNB;   // B*L*K*HID floats

    unsigned char* Wf8 = (unsigned char*)d_ws;   // 52 KiB

    const int nrow = 2 * LEN;
    topk_kernel<<<nrow + 52, 256, 0, stream>>>(X, mask, W_edge, (int*)Wf8, eidx);
    edge_kernel<<<nrow / 8, 512, 0, stream>>>(X, Ridx, Chain, W_pos, b_pos, Wf8,
                                              lng, lnb, eidx, E);
}